// Round 1
// baseline (1022.087 us; speedup 1.0000x reference)
//
#include <hip/hip_runtime.h>

// Problem constants
#define HALF   20000
#define MSEL   6001        // top-30% count: 20000 - int(0.7*20000)=13999 -> 6001
#define RANKLO 13999
#define NBUCK  4096
#define TPB    512
#define NT     12          // target tiles of 512 (12*512 = 6144 >= 6001)
#define NC     16          // source chunks
#define CH     376         // chunk size (15*376 + 361 = 6001)
#define MPAD   6144
#define NBLK   (NT*NC)     // 192

// Workspace offsets (in 4-byte elements)
#define OFF_HIST   0        // int[2][4096]
#define OFF_TSEL   8192     // int[2]
#define OFF_CCNT   8194     // int[2]
#define OFF_ZERO_N 8196
#define OFF_CANDV  8704     // float[2][8192]
#define OFF_CANDI  25088    // int[2][8192]
#define OFF_XS     41472    // float[6144] sorted top of half0
#define OFF_YS     47616    // float[6144] sorted top of half1
#define OFF_MM     53760    // float[192] meanM partials
#define OFF_LAM    53952    // {lam2, delta, kd}
#define OFF_CST    53956    // {Su, u_last, cconst}
#define OFF_ZST    53960    // {Sw, w_last, zconst}
#define OFF_VST    53964    // {Sv, v_last}
#define OFF_DP     53968    // float[192]
#define OFF_CP     54272    // float[16][6144] c partials
#define OFF_ZP     152576   // float[16][6144] z partials
// total = 250880 floats = ~0.96 MB of d_ws

__device__ __forceinline__ float fexp2(float x) {
#if defined(__has_builtin)
#if __has_builtin(__builtin_amdgcn_exp2f)
  return __builtin_amdgcn_exp2f(x);
#else
  return exp2f(x);
#endif
#else
  return exp2f(x);
#endif
}

__device__ __forceinline__ int bucket_of(float v) {
  int b = (int)(v * 4096.0f);
  b = b < 0 ? 0 : b;
  b = b > (NBUCK - 1) ? (NBUCK - 1) : b;
  return b;
}

__global__ __launch_bounds__(512) void k_zero(int* wsI) {
  int i = blockIdx.x * blockDim.x + threadIdx.x;
  if (i < OFF_ZERO_N) wsI[i] = 0;
}

__global__ __launch_bounds__(512) void k_hist(const float* __restrict__ yp, int* wsI) {
  int i = blockIdx.x * blockDim.x + threadIdx.x;
  if (i >= 2 * HALF) return;
  int h = (i >= HALF) ? 1 : 0;
  atomicAdd(&wsI[OFF_HIST + h * NBUCK + bucket_of(yp[i])], 1);
}

// find threshold bucket t*: largest t with (#elements in buckets >= t) >= MSEL
__global__ __launch_bounds__(1024) void k_findt(int* wsI) {
  __shared__ int ss[1024];
  const int h = blockIdx.x;
  const int t = threadIdx.x;
  const int* hist = wsI + OFF_HIST + h * NBUCK;
  int c0 = hist[4 * t + 0], c1 = hist[4 * t + 1], c2 = hist[4 * t + 2], c3 = hist[4 * t + 3];
  ss[t] = c0 + c1 + c2 + c3;
  __syncthreads();
  // inclusive suffix scan over thread sums
  for (int off = 1; off < 1024; off <<= 1) {
    int v = ss[t];
    if (t + off < 1024) v += ss[t + off];
    __syncthreads();
    ss[t] = v;
    __syncthreads();
  }
  int SSnext = (t < 1023) ? ss[t + 1] : 0;  // suffix starting at bucket 4(t+1)
  int R3 = c3 + SSnext;
  int R2 = c2 + R3;
  int R1 = c1 + R2;
  int R0 = c0 + R1;
  // R(b) >= MSEL and R(b+1) < MSEL  -> exactly one bucket
  if (R0 >= MSEL && R1 < MSEL) wsI[OFF_TSEL + h] = 4 * t + 0;
  if (R1 >= MSEL && R2 < MSEL) wsI[OFF_TSEL + h] = 4 * t + 1;
  if (R2 >= MSEL && R3 < MSEL) wsI[OFF_TSEL + h] = 4 * t + 2;
  if (R3 >= MSEL && SSnext < MSEL) wsI[OFF_TSEL + h] = 4 * t + 3;
}

__global__ __launch_bounds__(512) void k_cand(const float* __restrict__ yp, int* wsI, float* wsF) {
  int i = blockIdx.x * blockDim.x + threadIdx.x;
  if (i >= 2 * HALF) return;
  int h = (i >= HALF) ? 1 : 0;
  int li = i - h * HALF;
  float v = yp[i];
  if (bucket_of(v) < wsI[OFF_TSEL + h]) return;
  int pos = atomicAdd(&wsI[OFF_CCNT + h], 1);
  if (pos < 8192) {
    wsF[OFF_CANDV + h * 8192 + pos] = v;
    wsI[OFF_CANDI + h * 8192 + pos] = li;
  }
}

// exact rank of each candidate within its half; place top MSEL sorted.
__global__ __launch_bounds__(256) void k_rank(const float* __restrict__ yp, const int* wsI, float* wsF) {
  __shared__ float buf[2048];
  const int h = blockIdx.y;
  const int g = blockIdx.x * blockDim.x + threadIdx.x;
  const int cnt = wsI[OFF_CCNT + h];
  const bool cand = (g < cnt);
  float v = 0.f;
  int li = 0;
  if (cand) {
    v = wsF[OFF_CANDV + h * 8192 + g];
    li = wsI[OFF_CANDI + h * 8192 + g];
  }
  const float* src = yp + h * HALF;
  int r = 0;
  for (int base = 0; base < HALF; base += 2048) {
    int len = min(2048, HALF - base);
    for (int l = threadIdx.x; l < len; l += blockDim.x) buf[l] = src[base + l];
    __syncthreads();
    if (cand) {
      for (int l = 0; l < len; ++l) {
        float w = buf[l];
        int j = base + l;
        r += (w < v || (w == v && j < li)) ? 1 : 0;
      }
    }
    __syncthreads();
  }
  if (cand && r >= RANKLO) {
    wsF[(h ? OFF_YS : OFF_XS) + (r - RANKLO)] = v;
  }
}

// meanM partial sums: sum_{tile x chunk} |x_t - y_s|
__global__ __launch_bounds__(TPB) void k_mm(float* wsF) {
  __shared__ float sval[CH];
  __shared__ float red[TPB];
  const int tid = threadIdx.x;
  const int tile = blockIdx.x % NT, chunk = blockIdx.x / NT;
  const int tgt = tile * TPB + tid;
  const int cbase = chunk * CH;
  const int chlen = min(CH, MSEL - cbase);
  for (int s = tid; s < chlen; s += TPB) sval[s] = wsF[OFF_YS + cbase + s];
  __syncthreads();
  float acc = 0.f;
  if (tgt < MSEL) {
    float xt = wsF[OFF_XS + tgt];
    for (int s = 0; s < chlen; ++s) acc += fabsf(xt - sval[s]);
  }
  red[tid] = acc;
  __syncthreads();
  for (int s = TPB / 2; s > 0; s >>= 1) {
    if (tid < s) red[tid] += red[tid + s];
    __syncthreads();
  }
  if (tid == 0) wsF[OFF_MM + blockIdx.x] = red[0];
}

__global__ __launch_bounds__(256) void k_lam(float* wsF) {
  __shared__ float red[256];
  const int t = threadIdx.x;
  red[t] = (t < NBLK) ? wsF[OFF_MM + t] : 0.f;
  __syncthreads();
  for (int s = 128; s > 0; s >>= 1) {
    if (t < s) red[t] += red[t + s];
    __syncthreads();
  }
  if (t == 0) {
    float meanM = red[0] / ((float)MSEL * (float)MSEL);
    float lam = 10.0f / meanM;
    float x0 = wsF[OFF_XS + 0], xl = wsF[OFF_XS + MSEL - 1];
    float y0v = wsF[OFF_YS + 0], yl = wsF[OFF_YS + MSEL - 1];
    float delta = fmaxf(yl - x0, xl - y0v);
    float lam2 = -lam * 1.4426950408889634f;  // for exp2
    float kd = fexp2(lam2 * delta) + 1e-6f;
    wsF[OFF_LAM + 0] = lam2;
    wsF[OFF_LAM + 1] = delta;
    wsF[OFF_LAM + 2] = kd;
  }
}

// One Sinkhorn half-step. Symmetric in the two sides (a==b vectors).
// Computes dual weights for its source chunk from part_in + state_in,
// then brute-force partial matvec into part_out; block 0 writes state_out.
__global__ __launch_bounds__(TPB) void k_sink(float* wsF, int src_off, int tgt_off,
                                              int pin_off, int pout_off,
                                              int stin_off, int stout_off, int first) {
  __shared__ float sval[CH];
  __shared__ float swgt[CH];
  __shared__ float red[TPB];
  const int tid = threadIdx.x;
  const int tile = blockIdx.x % NT, chunk = blockIdx.x / NT;
  const int tgt = tile * TPB + tid;
  const int cbase = chunk * CH;
  const int chlen = min(CH, MSEL - cbase);
  const float au = 0.5f / 20000.0f;
  const float lam2 = wsF[OFF_LAM + 0];
  const float kd = wsF[OFF_LAM + 2];

  for (int s = tid; s < chlen; s += TPB) sval[s] = wsF[src_off + cbase + s];

  float S, lastv;
  if (first) {
    for (int s = tid; s < chlen; s += TPB) swgt[s] = au;
    S = (float)MSEL * au;
    lastv = 0.5f;
  } else {
    float Sin = wsF[stin_off + 0];
    float lin = wsF[stin_off + 1];
    float cin = wsF[stin_off + 2];
    float zlast = kd * Sin + lin * (1.0f + 1e-6f);
    lastv = 0.5f / zlast;
    float sacc = 0.f;
    for (int i = tid; i < MSEL; i += TPB) {
      float z = 0.f;
#pragma unroll
      for (int cc = 0; cc < NC; ++cc) z += wsF[pin_off + cc * MPAD + i];
      z += cin;
      float uu = au / z;
      sacc += uu;
      int rs = i - cbase;
      if (rs >= 0 && rs < chlen) swgt[rs] = uu;
    }
    red[tid] = sacc;
    __syncthreads();
    for (int s2 = TPB / 2; s2 > 0; s2 >>= 1) {
      if (tid < s2) red[tid] += red[tid + s2];
      __syncthreads();
    }
    S = red[0];
  }
  if (blockIdx.x == 0 && tid == 0) {
    wsF[stout_off + 0] = S;
    wsF[stout_off + 1] = lastv;
    wsF[stout_off + 2] = 1e-6f * S + lastv * kd;
  }
  __syncthreads();

  float xt = (tgt < MSEL) ? wsF[tgt_off + tgt] : 0.f;
  float acc = 0.f;
#pragma unroll 4
  for (int s = 0; s < chlen; ++s) {
    float d = fabsf(xt - sval[s]);
    acc += swgt[s] * fexp2(lam2 * d);
  }
  if (tgt < MSEL) wsF[pout_off + chunk * MPAD + tgt] = acc;
}

// Final pass: v from c_part (after 11th c-pass), u from z_part, partial D sums.
__global__ __launch_bounds__(TPB) void k_dpass(float* wsF) {
  __shared__ float sval[CH];
  __shared__ float swgt[CH];
  __shared__ float red[TPB];
  const int tid = threadIdx.x;
  const int tile = blockIdx.x % NT, chunk = blockIdx.x / NT;
  const int tgt = tile * TPB + tid;
  const int cbase = chunk * CH;
  const int chlen = min(CH, MSEL - cbase);
  const float au = 0.5f / 20000.0f;
  const float lam2 = wsF[OFF_LAM + 0];
  const float kd = wsF[OFF_LAM + 2];
  const float Su = wsF[OFF_CST + 0];
  const float u_last = wsF[OFF_CST + 1];
  const float cconst = wsF[OFF_CST + 2];
  const float zconst = wsF[OFF_ZST + 2];

  for (int s = tid; s < chlen; s += TPB) sval[s] = wsF[OFF_XS + cbase + s];

  float c_last = kd * Su + u_last * (1.0f + 1e-6f);
  float v_last = 0.5f / c_last;
  float sacc = 0.f;
  for (int j = tid; j < MSEL; j += TPB) {
    float c = 0.f;
#pragma unroll
    for (int cc = 0; cc < NC; ++cc) c += wsF[OFF_CP + cc * MPAD + j];
    c += cconst;
    float vv = au / c;
    sacc += vv;
    int rs = j - cbase;
    if (rs >= 0 && rs < chlen) swgt[rs] = vv;
  }
  red[tid] = sacc;
  __syncthreads();
  for (int s2 = TPB / 2; s2 > 0; s2 >>= 1) {
    if (tid < s2) red[tid] += red[tid + s2];
    __syncthreads();
  }
  if (blockIdx.x == 0 && tid == 0) {
    wsF[OFF_VST + 0] = red[0];  // Sv
    wsF[OFF_VST + 1] = v_last;
  }
  __syncthreads();

  float dv = 0.f;
  if (tgt < MSEL) {
    float yt = wsF[OFF_YS + tgt];
    float z = 0.f;
#pragma unroll
    for (int cc = 0; cc < NC; ++cc) z += wsF[OFF_ZP + cc * MPAD + tgt];
    z += zconst;
    float uti = au / z;
    float acc = 0.f;
#pragma unroll 4
    for (int s = 0; s < chlen; ++s) {
      float d = fabsf(yt - sval[s]);
      float e = fexp2(lam2 * d);
      acc += swgt[s] * ((e + 1e-6f) * d);
    }
    dv = uti * acc;
  }
  red[tid] = dv;
  __syncthreads();
  for (int s2 = TPB / 2; s2 > 0; s2 >>= 1) {
    if (tid < s2) red[tid] += red[tid + s2];
    __syncthreads();
  }
  if (tid == 0) wsF[OFF_DP + blockIdx.x] = red[0];
}

__global__ __launch_bounds__(256) void k_fin(float* wsF, float* out) {
  __shared__ float red[256];
  const int t = threadIdx.x;
  red[t] = (t < NBLK) ? wsF[OFF_DP + t] : 0.f;
  __syncthreads();
  for (int s = 128; s > 0; s >>= 1) {
    if (t < s) red[t] += red[t + s];
    __syncthreads();
  }
  if (t == 0) {
    float delta = wsF[OFF_LAM + 1];
    float kd = wsF[OFF_LAM + 2];
    float Su = wsF[OFF_CST + 0];
    float u_last = wsF[OFF_CST + 1];
    float Sv = wsF[OFF_VST + 0];
    float v_last = wsF[OFF_VST + 1];
    float D = red[0] + delta * kd * (u_last * Sv + v_last * Su);
    out[0] = 2.0f * D;
    out[1] = 0.f;
    out[2] = 0.f;
    out[3] = 0.f;
  }
}

extern "C" void kernel_launch(void* const* d_in, const int* in_sizes, int n_in,
                              void* d_out, int out_size, void* d_ws, size_t ws_size,
                              hipStream_t stream) {
  const float* yp = (const float*)d_in[0];
  float* wsF = (float*)d_ws;
  int* wsI = (int*)d_ws;
  float* out = (float*)d_out;

  k_zero<<<17, 512, 0, stream>>>(wsI);
  k_hist<<<79, 512, 0, stream>>>(yp, wsI);
  k_findt<<<2, 1024, 0, stream>>>(wsI);
  k_cand<<<79, 512, 0, stream>>>(yp, wsI, wsF);
  k_rank<<<dim3(32, 2), 256, 0, stream>>>(yp, wsI, wsF);
  k_mm<<<NBLK, TPB, 0, stream>>>(wsF);
  k_lam<<<1, 256, 0, stream>>>(wsF);

  // Sinkhorn: 11 c-passes (src=ys -> targets xs), 10 z-passes, interleaved.
  k_sink<<<NBLK, TPB, 0, stream>>>(wsF, OFF_YS, OFF_XS, OFF_ZP, OFF_CP, OFF_ZST, OFF_CST, 1);
  for (int it = 0; it < 10; ++it) {
    k_sink<<<NBLK, TPB, 0, stream>>>(wsF, OFF_XS, OFF_YS, OFF_CP, OFF_ZP, OFF_CST, OFF_ZST, 0);
    k_sink<<<NBLK, TPB, 0, stream>>>(wsF, OFF_YS, OFF_XS, OFF_ZP, OFF_CP, OFF_ZST, OFF_CST, 0);
  }
  k_dpass<<<NBLK, TPB, 0, stream>>>(wsF);
  k_fin<<<1, 256, 0, stream>>>(wsF, out);
}

// Round 2
// 541.390 us; speedup vs baseline: 1.8879x; 1.8879x over previous
//
#include <hip/hip_runtime.h>

// Problem constants
#define HALF   20000
#define MSEL   6001        // top-30% count: 20000 - int(0.7*20000)=13999 -> 6001
#define RANKLO 13999       // = HALF - MSEL
#define NBUCK  4096
#define TPB    512
#define NT     12          // target tiles of 512 (12*512 = 6144 >= 6001)
#define NC     16          // source chunks
#define CH     376         // chunk size (15*376 + 361 = 6001)
#define MPAD   6144
#define NBLK   (NT*NC)     // 192
#define CANDMAX 8192

// Workspace offsets (in 4-byte elements)
#define OFF_HIST   0        // int[2][4096]
#define OFF_TSEL   8192     // int[2]
#define OFF_CCNT   8194     // int[2]
#define OFF_ZERO_N 8196
#define OFF_CANDV  8704     // float[2][8192]
#define OFF_CANDI  25088    // int[2][8192]
#define OFF_XS     41472    // float[6144] sorted top of half0
#define OFF_YS     47616    // float[6144] sorted top of half1
#define OFF_MM     53760    // float[192] meanM partials
#define OFF_LAM    53952    // {lam2, delta, kd}
#define OFF_CST    53956    // {Su, u_last, cconst}
#define OFF_ZST    53960    // {Sw, w_last, zconst}
#define OFF_VST    53964    // {Sv, v_last}
#define OFF_DP     53968    // float[192]
#define OFF_CP     54272    // float[16][6144] c partials
#define OFF_ZP     152576   // float[16][6144] z partials
#define OFF_RANK   250880   // int[2][8192] candidate ranks
// total = 267264 elems ~= 1.04 MB of d_ws

__device__ __forceinline__ float fexp2(float x) {
#if defined(__has_builtin)
#if __has_builtin(__builtin_amdgcn_exp2f)
  return __builtin_amdgcn_exp2f(x);
#else
  return exp2f(x);
#endif
#else
  return exp2f(x);
#endif
}

__device__ __forceinline__ int bucket_of(float v) {
  int b = (int)(v * 4096.0f);
  b = b < 0 ? 0 : b;
  b = b > (NBUCK - 1) ? (NBUCK - 1) : b;
  return b;
}

__global__ __launch_bounds__(512) void k_zero(int* wsI) {
  int i = blockIdx.x * blockDim.x + threadIdx.x;
  if (i < OFF_ZERO_N) wsI[i] = 0;
  if (i < 2 * CANDMAX) wsI[OFF_RANK + i] = 0;
}

__global__ __launch_bounds__(512) void k_hist(const float* __restrict__ yp, int* wsI) {
  int i = blockIdx.x * blockDim.x + threadIdx.x;
  if (i >= 2 * HALF) return;
  int h = (i >= HALF) ? 1 : 0;
  atomicAdd(&wsI[OFF_HIST + h * NBUCK + bucket_of(yp[i])], 1);
}

// find threshold bucket t*: largest t with (#elements in buckets >= t) >= MSEL
__global__ __launch_bounds__(1024) void k_findt(int* wsI) {
  __shared__ int ss[1024];
  const int h = blockIdx.x;
  const int t = threadIdx.x;
  const int* hist = wsI + OFF_HIST + h * NBUCK;
  int c0 = hist[4 * t + 0], c1 = hist[4 * t + 1], c2 = hist[4 * t + 2], c3 = hist[4 * t + 3];
  ss[t] = c0 + c1 + c2 + c3;
  __syncthreads();
  for (int off = 1; off < 1024; off <<= 1) {
    int v = ss[t];
    if (t + off < 1024) v += ss[t + off];
    __syncthreads();
    ss[t] = v;
    __syncthreads();
  }
  int SSnext = (t < 1023) ? ss[t + 1] : 0;
  int R3 = c3 + SSnext;
  int R2 = c2 + R3;
  int R1 = c1 + R2;
  int R0 = c0 + R1;
  if (R0 >= MSEL && R1 < MSEL) wsI[OFF_TSEL + h] = 4 * t + 0;
  if (R1 >= MSEL && R2 < MSEL) wsI[OFF_TSEL + h] = 4 * t + 1;
  if (R2 >= MSEL && R3 < MSEL) wsI[OFF_TSEL + h] = 4 * t + 2;
  if (R3 >= MSEL && SSnext < MSEL) wsI[OFF_TSEL + h] = 4 * t + 3;
}

__global__ __launch_bounds__(512) void k_cand(const float* __restrict__ yp, int* wsI, float* wsF) {
  int i = blockIdx.x * blockDim.x + threadIdx.x;
  if (i >= 2 * HALF) return;
  int h = (i >= HALF) ? 1 : 0;
  int li = i - h * HALF;
  float v = yp[i];
  if (bucket_of(v) < wsI[OFF_TSEL + h]) return;
  int pos = atomicAdd(&wsI[OFF_CCNT + h], 1);
  if (pos < CANDMAX) {
    wsF[OFF_CANDV + h * CANDMAX + pos] = v;
    wsI[OFF_CANDI + h * CANDMAX + pos] = li;
  }
}

// rank among candidates only: grid (tile, chunk, half). Each block stages a
// 512-candidate chunk in LDS; each thread counts how many chunk elements are
// smaller than its candidate (tie-break by original index), atomicAdd partial.
__global__ __launch_bounds__(512) void k_rankc(const int* __restrict__ wsIc, float* wsF, int* wsI) {
  __shared__ float cv[512];
  __shared__ int ci[512];
  const int h = blockIdx.z;
  const int tid = threadIdx.x;
  const int cnt = min(wsIc[OFF_CCNT + h], CANDMAX);
  const int cb = blockIdx.y * 512;
  if (cb >= cnt) return;
  const int clen = min(512, cnt - cb);
  if (tid < clen) {
    cv[tid] = wsF[OFF_CANDV + h * CANDMAX + cb + tid];
    ci[tid] = wsIc[OFF_CANDI + h * CANDMAX + cb + tid];
  }
  __syncthreads();
  const int g = blockIdx.x * 512 + tid;
  if (g >= cnt) return;
  const float v = wsF[OFF_CANDV + h * CANDMAX + g];
  const int li = wsIc[OFF_CANDI + h * CANDMAX + g];
  int r = 0;
  for (int l = 0; l < clen; ++l) {
    float w = cv[l];
    r += (w < v || (w == v && ci[l] < li)) ? 1 : 0;
  }
  atomicAdd(&wsI[OFF_RANK + h * CANDMAX + g], r);
}

// place: full rank = (HALF - cnt) + rank_among; keep if >= RANKLO.
__global__ __launch_bounds__(512) void k_place(const int* __restrict__ wsI, float* wsF) {
  const int h = blockIdx.y;
  const int g = blockIdx.x * 512 + threadIdx.x;
  const int cnt = min(wsI[OFF_CCNT + h], CANDMAX);
  if (g >= cnt) return;
  const int full = wsI[OFF_RANK + h * CANDMAX + g] + (HALF - cnt);
  if (full >= RANKLO) {
    wsF[(h ? OFF_YS : OFF_XS) + (full - RANKLO)] = wsF[OFF_CANDV + h * CANDMAX + g];
  }
}

// meanM partial sums: sum_{tile x chunk} |x_t - y_s|
__global__ __launch_bounds__(TPB) void k_mm(float* wsF) {
  __shared__ float sval[CH];
  __shared__ float red[TPB];
  const int tid = threadIdx.x;
  const int tile = blockIdx.x % NT, chunk = blockIdx.x / NT;
  const int tgt = tile * TPB + tid;
  const int cbase = chunk * CH;
  const int chlen = min(CH, MSEL - cbase);
  for (int s = tid; s < chlen; s += TPB) sval[s] = wsF[OFF_YS + cbase + s];
  __syncthreads();
  float acc = 0.f;
  if (tgt < MSEL) {
    float xt = wsF[OFF_XS + tgt];
    for (int s = 0; s < chlen; ++s) acc += fabsf(xt - sval[s]);
  }
  red[tid] = acc;
  __syncthreads();
  for (int s = TPB / 2; s > 0; s >>= 1) {
    if (tid < s) red[tid] += red[tid + s];
    __syncthreads();
  }
  if (tid == 0) wsF[OFF_MM + blockIdx.x] = red[0];
}

__global__ __launch_bounds__(256) void k_lam(float* wsF) {
  __shared__ float red[256];
  const int t = threadIdx.x;
  red[t] = (t < NBLK) ? wsF[OFF_MM + t] : 0.f;
  __syncthreads();
  for (int s = 128; s > 0; s >>= 1) {
    if (t < s) red[t] += red[t + s];
    __syncthreads();
  }
  if (t == 0) {
    float meanM = red[0] / ((float)MSEL * (float)MSEL);
    float lam = 10.0f / meanM;
    float x0 = wsF[OFF_XS + 0], xl = wsF[OFF_XS + MSEL - 1];
    float y0v = wsF[OFF_YS + 0], yl = wsF[OFF_YS + MSEL - 1];
    float delta = fmaxf(yl - x0, xl - y0v);
    float lam2 = -lam * 1.4426950408889634f;  // for exp2
    float kd = fexp2(lam2 * delta) + 1e-6f;
    wsF[OFF_LAM + 0] = lam2;
    wsF[OFF_LAM + 1] = delta;
    wsF[OFF_LAM + 2] = kd;
  }
}

// One Sinkhorn half-step.
__global__ __launch_bounds__(TPB) void k_sink(float* wsF, int src_off, int tgt_off,
                                              int pin_off, int pout_off,
                                              int stin_off, int stout_off, int first) {
  __shared__ float sval[CH];
  __shared__ float swgt[CH];
  __shared__ float red[TPB];
  const int tid = threadIdx.x;
  const int tile = blockIdx.x % NT, chunk = blockIdx.x / NT;
  const int tgt = tile * TPB + tid;
  const int cbase = chunk * CH;
  const int chlen = min(CH, MSEL - cbase);
  const float au = 0.5f / 20000.0f;
  const float lam2 = wsF[OFF_LAM + 0];
  const float kd = wsF[OFF_LAM + 2];

  for (int s = tid; s < chlen; s += TPB) sval[s] = wsF[src_off + cbase + s];

  float S, lastv;
  if (first) {
    for (int s = tid; s < chlen; s += TPB) swgt[s] = au;
    S = (float)MSEL * au;
    lastv = 0.5f;
  } else {
    float Sin = wsF[stin_off + 0];
    float lin = wsF[stin_off + 1];
    float cin = wsF[stin_off + 2];
    float zlast = kd * Sin + lin * (1.0f + 1e-6f);
    lastv = 0.5f / zlast;
    float sacc = 0.f;
    for (int i = tid; i < MSEL; i += TPB) {
      float z = 0.f;
#pragma unroll
      for (int cc = 0; cc < NC; ++cc) z += wsF[pin_off + cc * MPAD + i];
      z += cin;
      float uu = au / z;
      sacc += uu;
      int rs = i - cbase;
      if (rs >= 0 && rs < chlen) swgt[rs] = uu;
    }
    red[tid] = sacc;
    __syncthreads();
    for (int s2 = TPB / 2; s2 > 0; s2 >>= 1) {
      if (tid < s2) red[tid] += red[tid + s2];
      __syncthreads();
    }
    S = red[0];
  }
  if (blockIdx.x == 0 && tid == 0) {
    wsF[stout_off + 0] = S;
    wsF[stout_off + 1] = lastv;
    wsF[stout_off + 2] = 1e-6f * S + lastv * kd;
  }
  __syncthreads();

  float xt = (tgt < MSEL) ? wsF[tgt_off + tgt] : 0.f;
  float acc = 0.f;
#pragma unroll 4
  for (int s = 0; s < chlen; ++s) {
    float d = fabsf(xt - sval[s]);
    acc += swgt[s] * fexp2(lam2 * d);
  }
  if (tgt < MSEL) wsF[pout_off + chunk * MPAD + tgt] = acc;
}

// Final pass: v from c_part (after 11th c-pass), u from z_part, partial D sums.
__global__ __launch_bounds__(TPB) void k_dpass(float* wsF) {
  __shared__ float sval[CH];
  __shared__ float swgt[CH];
  __shared__ float red[TPB];
  const int tid = threadIdx.x;
  const int tile = blockIdx.x % NT, chunk = blockIdx.x / NT;
  const int tgt = tile * TPB + tid;
  const int cbase = chunk * CH;
  const int chlen = min(CH, MSEL - cbase);
  const float au = 0.5f / 20000.0f;
  const float lam2 = wsF[OFF_LAM + 0];
  const float kd = wsF[OFF_LAM + 2];
  const float Su = wsF[OFF_CST + 0];
  const float u_last = wsF[OFF_CST + 1];
  const float cconst = wsF[OFF_CST + 2];
  const float zconst = wsF[OFF_ZST + 2];

  for (int s = tid; s < chlen; s += TPB) sval[s] = wsF[OFF_XS + cbase + s];

  float c_last = kd * Su + u_last * (1.0f + 1e-6f);
  float v_last = 0.5f / c_last;
  float sacc = 0.f;
  for (int j = tid; j < MSEL; j += TPB) {
    float c = 0.f;
#pragma unroll
    for (int cc = 0; cc < NC; ++cc) c += wsF[OFF_CP + cc * MPAD + j];
    c += cconst;
    float vv = au / c;
    sacc += vv;
    int rs = j - cbase;
    if (rs >= 0 && rs < chlen) swgt[rs] = vv;
  }
  red[tid] = sacc;
  __syncthreads();
  for (int s2 = TPB / 2; s2 > 0; s2 >>= 1) {
    if (tid < s2) red[tid] += red[tid + s2];
    __syncthreads();
  }
  if (blockIdx.x == 0 && tid == 0) {
    wsF[OFF_VST + 0] = red[0];  // Sv
    wsF[OFF_VST + 1] = v_last;
  }
  __syncthreads();

  float dv = 0.f;
  if (tgt < MSEL) {
    float yt = wsF[OFF_YS + tgt];
    float z = 0.f;
#pragma unroll
    for (int cc = 0; cc < NC; ++cc) z += wsF[OFF_ZP + cc * MPAD + tgt];
    z += zconst;
    float uti = au / z;
    float acc = 0.f;
#pragma unroll 4
    for (int s = 0; s < chlen; ++s) {
      float d = fabsf(yt - sval[s]);
      float e = fexp2(lam2 * d);
      acc += swgt[s] * ((e + 1e-6f) * d);
    }
    dv = uti * acc;
  }
  red[tid] = dv;
  __syncthreads();
  for (int s2 = TPB / 2; s2 > 0; s2 >>= 1) {
    if (tid < s2) red[tid] += red[tid + s2];
    __syncthreads();
  }
  if (tid == 0) wsF[OFF_DP + blockIdx.x] = red[0];
}

__global__ __launch_bounds__(256) void k_fin(float* wsF, float* out) {
  __shared__ float red[256];
  const int t = threadIdx.x;
  red[t] = (t < NBLK) ? wsF[OFF_DP + t] : 0.f;
  __syncthreads();
  for (int s = 128; s > 0; s >>= 1) {
    if (t < s) red[t] += red[t + s];
    __syncthreads();
  }
  if (t == 0) {
    float delta = wsF[OFF_LAM + 1];
    float kd = wsF[OFF_LAM + 2];
    float Su = wsF[OFF_CST + 0];
    float u_last = wsF[OFF_CST + 1];
    float Sv = wsF[OFF_VST + 0];
    float v_last = wsF[OFF_VST + 1];
    float D = red[0] + delta * kd * (u_last * Sv + v_last * Su);
    out[0] = 2.0f * D;
    out[1] = 0.f;
    out[2] = 0.f;
    out[3] = 0.f;
  }
}

extern "C" void kernel_launch(void* const* d_in, const int* in_sizes, int n_in,
                              void* d_out, int out_size, void* d_ws, size_t ws_size,
                              hipStream_t stream) {
  const float* yp = (const float*)d_in[0];
  float* wsF = (float*)d_ws;
  int* wsI = (int*)d_ws;
  float* out = (float*)d_out;

  k_zero<<<49, 512, 0, stream>>>(wsI);
  k_hist<<<79, 512, 0, stream>>>(yp, wsI);
  k_findt<<<2, 1024, 0, stream>>>(wsI);
  k_cand<<<79, 512, 0, stream>>>(yp, wsI, wsF);
  k_rankc<<<dim3(16, 16, 2), 512, 0, stream>>>(wsI, wsF, wsI);
  k_place<<<dim3(16, 2), 512, 0, stream>>>(wsI, wsF);
  k_mm<<<NBLK, TPB, 0, stream>>>(wsF);
  k_lam<<<1, 256, 0, stream>>>(wsF);

  // Sinkhorn: 11 c-passes (src=ys -> targets xs), 10 z-passes, interleaved.
  k_sink<<<NBLK, TPB, 0, stream>>>(wsF, OFF_YS, OFF_XS, OFF_ZP, OFF_CP, OFF_ZST, OFF_CST, 1);
  for (int it = 0; it < 10; ++it) {
    k_sink<<<NBLK, TPB, 0, stream>>>(wsF, OFF_XS, OFF_YS, OFF_CP, OFF_ZP, OFF_CST, OFF_ZST, 0);
    k_sink<<<NBLK, TPB, 0, stream>>>(wsF, OFF_YS, OFF_XS, OFF_ZP, OFF_CP, OFF_ZST, OFF_CST, 0);
  }
  k_dpass<<<NBLK, TPB, 0, stream>>>(wsF);
  k_fin<<<1, 256, 0, stream>>>(wsF, out);
}

// Round 3
// 275.971 us; speedup vs baseline: 3.7036x; 1.9618x over previous
//
#include <hip/hip_runtime.h>

// Problem constants
#define HALF   20000
#define MSEL   6001        // top-30%: 20000 - int(0.7*20000)=13999 -> 6001
#define RANKLO 13999       // = HALF - MSEL
#define NBUCK  4096
#define TPB    512
#define NT     12          // target tiles of 512 (12*512 = 6144 >= 6001)
#define NC2    32          // source chunks
#define CH2    188         // 31*188=5828, last chunk 173; 32*188=6016>=6001
#define MPAD   6144
#define NBLK2  (NT*NC2)    // 384
#define CANDMAX 8192

// Workspace offsets (4-byte elements). CANDV/CANDI overlay ZP, RANK overlays CP
// (selection finishes before any matvec touches CP/ZP).
#define OFF_HIST   0        // int[2][4096]
#define OFF_TSEL   8192     // int[2]
#define OFF_CCNT   8194     // int[2]
#define OFF_ZERO_N 8196
#define OFF_XS     8704     // float[6144] sorted top of half0
#define OFF_YS     14848    // float[6144] sorted top of half1
#define OFF_MM     20992    // float[384]
#define OFF_LAM    21376    // {lam2, delta, kd}
#define OFF_SPX    21380    // float[32] partial sums of w (X side)
#define OFF_SPY    21412    // float[32] partial sums of u (Y side)
#define OFF_SPV    21444    // float[32] partial sums of v (final)
#define OFF_LX     21476    // lastv of X-side weights
#define OFF_LY     21477    // lastv of Y-side weights
#define OFF_DP     21480    // float[384]
#define OFF_CP     22016    // float[32][6144] partials toward X targets
#define OFF_ZP     218624   // float[32][6144] partials toward Y targets
#define OFF_CANDV  OFF_ZP            // float[2][8192]  (pre-matvec only)
#define OFF_CANDI  (OFF_ZP + 16384)  // int[2][8192]
#define OFF_RANK   OFF_CP            // int[2][8192]
// total = 415232 elems ~= 1.62 MB of d_ws

__device__ __forceinline__ float fexp2(float x) {
#if defined(__has_builtin)
#if __has_builtin(__builtin_amdgcn_exp2f)
  return __builtin_amdgcn_exp2f(x);
#else
  return exp2f(x);
#endif
#else
  return exp2f(x);
#endif
}

__device__ __forceinline__ int bucket_of(float v) {
  int b = (int)(v * 4096.0f);
  b = b < 0 ? 0 : b;
  b = b > (NBUCK - 1) ? (NBUCK - 1) : b;
  return b;
}

__global__ __launch_bounds__(512) void k_zero(int* wsI) {
  int i = blockIdx.x * blockDim.x + threadIdx.x;
  if (i < OFF_ZERO_N) wsI[i] = 0;
  if (i < 2 * CANDMAX) wsI[OFF_RANK + i] = 0;
}

__global__ __launch_bounds__(512) void k_hist(const float* __restrict__ yp, int* wsI) {
  int i = blockIdx.x * blockDim.x + threadIdx.x;
  if (i >= 2 * HALF) return;
  int h = (i >= HALF) ? 1 : 0;
  atomicAdd(&wsI[OFF_HIST + h * NBUCK + bucket_of(yp[i])], 1);
}

// find threshold bucket t*: largest t with (#elements in buckets >= t) >= MSEL
__global__ __launch_bounds__(1024) void k_findt(int* wsI) {
  __shared__ int ss[1024];
  const int h = blockIdx.x;
  const int t = threadIdx.x;
  const int* hist = wsI + OFF_HIST + h * NBUCK;
  int c0 = hist[4 * t + 0], c1 = hist[4 * t + 1], c2 = hist[4 * t + 2], c3 = hist[4 * t + 3];
  ss[t] = c0 + c1 + c2 + c3;
  __syncthreads();
  for (int off = 1; off < 1024; off <<= 1) {
    int v = ss[t];
    if (t + off < 1024) v += ss[t + off];
    __syncthreads();
    ss[t] = v;
    __syncthreads();
  }
  int SSnext = (t < 1023) ? ss[t + 1] : 0;
  int R3 = c3 + SSnext;
  int R2 = c2 + R3;
  int R1 = c1 + R2;
  int R0 = c0 + R1;
  if (R0 >= MSEL && R1 < MSEL) wsI[OFF_TSEL + h] = 4 * t + 0;
  if (R1 >= MSEL && R2 < MSEL) wsI[OFF_TSEL + h] = 4 * t + 1;
  if (R2 >= MSEL && R3 < MSEL) wsI[OFF_TSEL + h] = 4 * t + 2;
  if (R3 >= MSEL && SSnext < MSEL) wsI[OFF_TSEL + h] = 4 * t + 3;
}

// candidate compaction: one atomic per block via LDS inclusive scan.
__global__ __launch_bounds__(512) void k_cand(const float* __restrict__ yp, int* wsI, float* wsF) {
  __shared__ int ss[512];
  __shared__ int sbase;
  const int h = blockIdx.y;
  const int tid = threadIdx.x;
  const int idx = blockIdx.x * 512 + tid;
  float v = 0.f;
  int flag = 0;
  if (idx < HALF) {
    v = yp[h * HALF + idx];
    flag = (bucket_of(v) >= wsI[OFF_TSEL + h]) ? 1 : 0;
  }
  ss[tid] = flag;
  __syncthreads();
  for (int off = 1; off < 512; off <<= 1) {
    int add = (tid >= off) ? ss[tid - off] : 0;
    __syncthreads();
    ss[tid] += add;
    __syncthreads();
  }
  if (tid == 511) sbase = atomicAdd(&wsI[OFF_CCNT + h], ss[511]);
  __syncthreads();
  if (flag) {
    int pos = sbase + ss[tid] - 1;
    if (pos < CANDMAX) {
      wsF[OFF_CANDV + h * CANDMAX + pos] = v;
      wsI[OFF_CANDI + h * CANDMAX + pos] = idx;
    }
  }
}

// rank among candidates only (everything below threshold bucket is smaller).
__global__ __launch_bounds__(512) void k_rankc(const int* __restrict__ wsIc, float* wsF, int* wsI) {
  __shared__ float cv[512];
  __shared__ int ci[512];
  const int h = blockIdx.z;
  const int tid = threadIdx.x;
  const int cnt = min(wsIc[OFF_CCNT + h], CANDMAX);
  const int cb = blockIdx.y * 512;
  if (cb >= cnt) return;
  const int clen = min(512, cnt - cb);
  if (tid < clen) {
    cv[tid] = wsF[OFF_CANDV + h * CANDMAX + cb + tid];
    ci[tid] = wsIc[OFF_CANDI + h * CANDMAX + cb + tid];
  }
  __syncthreads();
  const int g = blockIdx.x * 512 + tid;
  if (g >= cnt) return;
  const float v = wsF[OFF_CANDV + h * CANDMAX + g];
  const int li = wsIc[OFF_CANDI + h * CANDMAX + g];
  int r = 0;
  for (int l = 0; l < clen; ++l) {
    float w = cv[l];
    r += (w < v || (w == v && ci[l] < li)) ? 1 : 0;
  }
  atomicAdd(&wsI[OFF_RANK + h * CANDMAX + g], r);
}

__global__ __launch_bounds__(512) void k_place(const int* __restrict__ wsI, float* wsF) {
  const int h = blockIdx.y;
  const int g = blockIdx.x * 512 + threadIdx.x;
  const int cnt = min(wsI[OFF_CCNT + h], CANDMAX);
  if (g >= cnt) return;
  const int full = wsI[OFF_RANK + h * CANDMAX + g] + (HALF - cnt);
  if (full >= RANKLO) {
    wsF[(h ? OFF_YS : OFF_XS) + (full - RANKLO)] = wsF[OFF_CANDV + h * CANDMAX + g];
  }
}

// meanM partial sums
__global__ __launch_bounds__(TPB) void k_mm(float* wsF) {
  __shared__ float sval[CH2];
  __shared__ float red[TPB];
  const int tid = threadIdx.x;
  const int tile = blockIdx.x % NT, chunk = blockIdx.x / NT;
  const int tgt = tile * TPB + tid;
  const int cbase = chunk * CH2;
  const int chlen = min(CH2, MSEL - cbase);
  if (tid < chlen) sval[tid] = wsF[OFF_YS + cbase + tid];
  __syncthreads();
  float acc = 0.f;
  if (tgt < MSEL) {
    float xt = wsF[OFF_XS + tgt];
    for (int s = 0; s < chlen; ++s) acc += fabsf(xt - sval[s]);
  }
  red[tid] = acc;
  __syncthreads();
  for (int s = TPB / 2; s > 0; s >>= 1) {
    if (tid < s) red[tid] += red[tid + s];
    __syncthreads();
  }
  if (tid == 0) wsF[OFF_MM + blockIdx.x] = red[0];
}

__global__ __launch_bounds__(512) void k_lam(float* wsF) {
  __shared__ float red[512];
  const int t = threadIdx.x;
  red[t] = (t < NBLK2) ? wsF[OFF_MM + t] : 0.f;
  __syncthreads();
  for (int s = 256; s > 0; s >>= 1) {
    if (t < s) red[t] += red[t + s];
    __syncthreads();
  }
  if (t == 0) {
    float meanM = red[0] / ((float)MSEL * (float)MSEL);
    float lam = 10.0f / meanM;
    float x0 = wsF[OFF_XS + 0], xl = wsF[OFF_XS + MSEL - 1];
    float y0v = wsF[OFF_YS + 0], yl = wsF[OFF_YS + MSEL - 1];
    float delta = fmaxf(yl - x0, xl - y0v);
    float lam2 = -lam * 1.4426950408889634f;  // for exp2
    float kd = fexp2(lam2 * delta) + 1e-6f;
    wsF[OFF_LAM + 0] = lam2;
    wsF[OFF_LAM + 1] = delta;
    wsF[OFF_LAM + 2] = kd;
  }
}

// Fused weight-prologue + matvec.
// mode 0: uniform weights au (very first pass, no SP/lastv writes)
// mode 1: prologue, fold = first-pass constants (S=MSEL*au, l=0.5)
// mode 2: prologue, fold = sum(spin[0..31]) + wsF[lin]
__global__ __launch_bounds__(TPB) void k_matvec(float* wsF, int src_off, int tgt_off,
                                                int pin_off, int pout_off,
                                                int spin_off, int spout_off,
                                                int lin_off, int lout_off, int mode) {
  __shared__ float2 sv[CH2];
  __shared__ float red[TPB];
  const int tid = threadIdx.x;
  const int tile = blockIdx.x % NT;
  const int chunk = blockIdx.x / NT;
  const int tgt = tile * TPB + tid;
  const int cbase = chunk * CH2;
  const int chlen = min(CH2, MSEL - cbase);
  const float au = 0.5f / 20000.0f;
  const float lam2 = wsF[OFF_LAM + 0];
  const float kd = wsF[OFF_LAM + 2];

  if (mode == 0) {
    if (tid < chlen) {
      float v = wsF[src_off + cbase + tid];
      sv[tid] = make_float2(lam2 * v, au);
    }
  } else {
    float S_in, l_in;
    if (mode == 1) {
      S_in = (float)MSEL * au;
      l_in = 0.5f;
    } else {
      S_in = 0.f;
#pragma unroll
      for (int k = 0; k < NC2; ++k) S_in += wsF[spin_off + k];
      l_in = wsF[lin_off];
    }
    const float cin = 1e-6f * S_in + l_in * kd;
    float w = 0.f;
    if (tid < chlen) {
      float z = cin;
#pragma unroll
      for (int cc = 0; cc < NC2; ++cc) z += wsF[pin_off + cc * MPAD + cbase + tid];
      w = au / z;
      float v = wsF[src_off + cbase + tid];
      sv[tid] = make_float2(lam2 * v, w);
    }
    red[tid] = w;
    __syncthreads();
    for (int s2 = TPB / 2; s2 > 0; s2 >>= 1) {
      if (tid < s2) red[tid] += red[tid + s2];
      __syncthreads();
    }
    if (tile == 0 && tid == 0) wsF[spout_off + chunk] = red[0];
    if (blockIdx.x == 0 && tid == 0)
      wsF[lout_off] = 0.5f / (kd * S_in + l_in * (1.0f + 1e-6f));
  }
  __syncthreads();

  if (tgt >= MSEL) return;
  const float xt = lam2 * wsF[tgt_off + tgt];
  float a0 = 0.f, a1 = 0.f, a2 = 0.f, a3 = 0.f;
  int s = 0;
  for (; s + 4 <= chlen; s += 4) {
    float2 p0 = sv[s], p1 = sv[s + 1], p2 = sv[s + 2], p3 = sv[s + 3];
    a0 += p0.y * fexp2(-fabsf(xt - p0.x));
    a1 += p1.y * fexp2(-fabsf(xt - p1.x));
    a2 += p2.y * fexp2(-fabsf(xt - p2.x));
    a3 += p3.y * fexp2(-fabsf(xt - p3.x));
  }
  for (; s < chlen; ++s) {
    float2 p = sv[s];
    a0 += p.y * fexp2(-fabsf(xt - p.x));
  }
  wsF[pout_off + chunk * MPAD + tgt] = (a0 + a1) + (a2 + a3);
}

// Final: v from CP (+cin from SPY/LY), u from ZP (+cin from SPX/LX), D partials.
__global__ __launch_bounds__(TPB) void k_dpass(float* wsF) {
  __shared__ float2 sv[CH2];  // (x value, v weight)
  __shared__ float red[TPB];
  const int tid = threadIdx.x;
  const int tile = blockIdx.x % NT;
  const int chunk = blockIdx.x / NT;
  const int tgt = tile * TPB + tid;
  const int cbase = chunk * CH2;
  const int chlen = min(CH2, MSEL - cbase);
  const float au = 0.5f / 20000.0f;
  const float lam2 = wsF[OFF_LAM + 0];
  const float kd = wsF[OFF_LAM + 2];

  float S_wx = 0.f, S_u = 0.f;
#pragma unroll
  for (int k = 0; k < NC2; ++k) {
    S_wx += wsF[OFF_SPX + k];
    S_u  += wsF[OFF_SPY + k];
  }
  const float lX = wsF[OFF_LX];
  const float lY = wsF[OFF_LY];
  const float cin_u = 1e-6f * S_wx + lX * kd;  // for u = au / (sum ZP + cin_u)
  const float cin_v = 1e-6f * S_u  + lY * kd;  // for v = au / (sum CP + cin_v)

  float vv = 0.f;
  if (tid < chlen) {
    float c = cin_v;
#pragma unroll
    for (int cc = 0; cc < NC2; ++cc) c += wsF[OFF_CP + cc * MPAD + cbase + tid];
    vv = au / c;
    sv[tid] = make_float2(wsF[OFF_XS + cbase + tid], vv);
  }
  red[tid] = vv;
  __syncthreads();
  for (int s2 = TPB / 2; s2 > 0; s2 >>= 1) {
    if (tid < s2) red[tid] += red[tid + s2];
    __syncthreads();
  }
  if (tile == 0 && tid == 0) wsF[OFF_SPV + chunk] = red[0];
  __syncthreads();

  float dv = 0.f;
  if (tgt < MSEL) {
    float z = cin_u;
#pragma unroll
    for (int cc = 0; cc < NC2; ++cc) z += wsF[OFF_ZP + cc * MPAD + tgt];
    float u = au / z;
    float yt = wsF[OFF_YS + tgt];
    float acc0 = 0.f, acc1 = 0.f;
    int s = 0;
    for (; s + 2 <= chlen; s += 2) {
      float2 p0 = sv[s], p1 = sv[s + 1];
      float d0 = fabsf(yt - p0.x);
      float d1 = fabsf(yt - p1.x);
      acc0 += p0.y * ((fexp2(lam2 * d0) + 1e-6f) * d0);
      acc1 += p1.y * ((fexp2(lam2 * d1) + 1e-6f) * d1);
    }
    for (; s < chlen; ++s) {
      float2 p = sv[s];
      float d = fabsf(yt - p.x);
      acc0 += p.y * ((fexp2(lam2 * d) + 1e-6f) * d);
    }
    dv = u * (acc0 + acc1);
  }
  red[tid] = dv;
  __syncthreads();
  for (int s2 = TPB / 2; s2 > 0; s2 >>= 1) {
    if (tid < s2) red[tid] += red[tid + s2];
    __syncthreads();
  }
  if (tid == 0) wsF[OFF_DP + blockIdx.x] = red[0];
}

__global__ __launch_bounds__(512) void k_fin(float* wsF, float* out) {
  __shared__ float red[512];
  const int t = threadIdx.x;
  red[t] = (t < NBLK2) ? wsF[OFF_DP + t] : 0.f;
  __syncthreads();
  for (int s = 256; s > 0; s >>= 1) {
    if (t < s) red[t] += red[t + s];
    __syncthreads();
  }
  if (t == 0) {
    float Su = 0.f, Sv = 0.f;
#pragma unroll
    for (int k = 0; k < NC2; ++k) {
      Su += wsF[OFF_SPY + k];
      Sv += wsF[OFF_SPV + k];
    }
    float u_last = wsF[OFF_LY];
    float delta = wsF[OFF_LAM + 1];
    float kd = wsF[OFF_LAM + 2];
    float v_last = 0.5f / (kd * Su + u_last * (1.0f + 1e-6f));
    float D = red[0] + delta * kd * (u_last * Sv + v_last * Su);
    out[0] = 2.0f * D;
    out[1] = 0.f;
    out[2] = 0.f;
    out[3] = 0.f;
  }
}

extern "C" void kernel_launch(void* const* d_in, const int* in_sizes, int n_in,
                              void* d_out, int out_size, void* d_ws, size_t ws_size,
                              hipStream_t stream) {
  const float* yp = (const float*)d_in[0];
  float* wsF = (float*)d_ws;
  int* wsI = (int*)d_ws;
  float* out = (float*)d_out;

  k_zero<<<48, 512, 0, stream>>>(wsI);
  k_hist<<<79, 512, 0, stream>>>(yp, wsI);
  k_findt<<<2, 1024, 0, stream>>>(wsI);
  k_cand<<<dim3(40, 2), 512, 0, stream>>>(yp, wsI, wsF);
  k_rankc<<<dim3(16, 16, 2), 512, 0, stream>>>(wsI, wsF, wsI);
  k_place<<<dim3(16, 2), 512, 0, stream>>>(wsI, wsF);
  k_mm<<<NBLK2, TPB, 0, stream>>>(wsF);
  k_lam<<<1, 512, 0, stream>>>(wsF);

  // matvec 1: YS -> XS with uniform u0 = au
  k_matvec<<<NBLK2, TPB, 0, stream>>>(wsF, OFF_YS, OFF_XS, 0, OFF_CP,
                                      0, 0, 0, 0, 0);
  for (int it = 0; it < 10; ++it) {
    // X -> Y: weights w_X from CP; state in = u-side (SPY/LY or constants)
    k_matvec<<<NBLK2, TPB, 0, stream>>>(wsF, OFF_XS, OFF_YS, OFF_CP, OFF_ZP,
                                        OFF_SPY, OFF_SPX, OFF_LY, OFF_LX,
                                        (it == 0) ? 1 : 2);
    // Y -> X: weights u from ZP; state in = w-side (SPX/LX)
    k_matvec<<<NBLK2, TPB, 0, stream>>>(wsF, OFF_YS, OFF_XS, OFF_ZP, OFF_CP,
                                        OFF_SPX, OFF_SPY, OFF_LX, OFF_LY, 2);
  }
  k_dpass<<<NBLK2, TPB, 0, stream>>>(wsF);
  k_fin<<<1, 512, 0, stream>>>(wsF, out);
}